// Round 8
// baseline (1057.898 us; speedup 1.0000x reference)
//
#include <hip/hip_runtime.h>
#include <hip/hip_bf16.h>
#include <stdint.h>

// CNF step: 4-layer tanh MLP (33->1024->1024->1024->32) forward + exact
// Jacobian trace via 32 forward-mode tangents. B=4096, H=1024, D=32.
// f32 in/out; bf16 MFMA internally.
//
// R8 (jvp GEMMs): two fixes on the R7 256x128/BK=32/pitch-40 core:
//  1. Bank-uniform WRITE permutation. R7 wrote rows {0,1,2,3} per 16-lane
//     phase -> granule starts {0,5,2,7} with 4-seg spans -> per-bank counts
//     up to 3 vs min 2 (SQ_LDS_BANK_CONFLICT 1.26e7). New mapping puts rows
//     {x,x+4,x+8,x+12} in each phase: starts 5x,5x+4,5x,5x+4 -> every bank
//     exactly 2x = free. Reads were already uniform (granule 5*r15+q4).
//  2. LDS ping-pong: write K-tile k+1 into buf^1 -> ONE barrier per K-tile
//     (was 2) and ds_writes interleave with MFMAs (no barrier between).
// Register-staged global prefetch kept. 61KB LDS, still 2 blocks/CU.

using bf  = __hip_bfloat16;
using bf2 = __hip_bfloat162;
typedef __attribute__((ext_vector_type(8))) short bf16x8;   // 8 bf16 = 4 VGPRs
typedef __attribute__((ext_vector_type(4))) float f32x4;    // C/D frag

__device__ __forceinline__ float b2f(bf x)    { return __bfloat162float(x); }
__device__ __forceinline__ bf    f2b(float x) { return __float2bfloat16(x); }

// ------------------------------------------------------- f32 -> bf16 convert
__global__ __launch_bounds__(256) void conv_k(const float* __restrict__ src,
                                              bf* __restrict__ dst, int n4) {
  const int i = blockIdx.x * 256 + threadIdx.x;
  if (i >= n4) return;
  float4 v = ((const float4*)src)[i];
  bf2* d = (bf2*)(dst + (size_t)i * 4);
  d[0] = __float22bfloat162_rn(make_float2(v.x, v.y));
  d[1] = __float22bfloat162_rn(make_float2(v.z, v.w));
}

// ------------------------------------------------- W0T bf16 (32x1024) from f32
__global__ void w0t_k(const float* __restrict__ W0, bf* __restrict__ W0T) {
  const int idx = blockIdx.x * 256 + threadIdx.x;  // 32768 total
  const int i = idx >> 10, q = idx & 1023;
  W0T[idx] = f2b(W0[q * 33 + i]);
}

// ---------------------------------------------------------------- fwd0
__global__ __launch_bounds__(256) void fwd0_k(const float* __restrict__ z,
                                              const float* __restrict__ tin,
                                              const float* __restrict__ W0,
                                              const float* __restrict__ b0,
                                              bf* __restrict__ h0) {
  __shared__ float zs[32 * 33];  // [s][k], k=32 is t
  const int t = threadIdx.x;
  const int s0 = blockIdx.x * 32;
  for (int j = t; j < 1024; j += 256) {
    const int s = j >> 5, k = j & 31;
    zs[s * 33 + k] = z[(size_t)(s0 + s) * 32 + k];
  }
  if (t < 32) zs[t * 33 + 32] = tin[0];
  __syncthreads();
#pragma unroll 1
  for (int rep = 0; rep < 4; ++rep) {
    const int hh = rep * 256 + t;
    const float* wr = W0 + (size_t)hh * 33;
    float wv[33];
#pragma unroll
    for (int k = 0; k < 33; ++k) wv[k] = wr[k];
    const float bv = b0[hh];
#pragma unroll 1
    for (int s = 0; s < 32; ++s) {
      float acc = bv;
#pragma unroll
      for (int k = 0; k < 33; ++k) acc += wv[k] * zs[s * 33 + k];
      h0[(size_t)(s0 + s) * 1024 + hh] = f2b(tanhf(acc));
    }
  }
}

// ---------------------------------------------------------------- fwd GEMM
// H[m][n] = tanh(sum_k A[m][k]*W[n][k] + bias[n]); M=4096, N=K=1024.
// 128x64 tile, BK=64, register-staged, XOR swizzle (R6 core, 0 conflicts).
__global__ __launch_bounds__(256) void gemm_fwd(const bf* __restrict__ A,
                                                const bf* __restrict__ W,
                                                const float* __restrict__ bias,
                                                bf* __restrict__ H) {
  constexpr int K = 1024, N = 1024;
  __shared__ __align__(16) bf As[128 * 64];
  __shared__ __align__(16) bf Bs[64 * 64];
  const int t = threadIdx.x, l = t & 63, w = t >> 6;
  const int wm = w >> 1, wn = w & 1;
  const int f = blockIdx.x;
  const int n_t = (f >> 3) & 15, m_t = (f & 7) + 8 * (f >> 7);
  const size_t m0 = (size_t)m_t * 128, n0 = (size_t)n_t * 64;
  const int r15 = l & 15, q4 = l >> 4, sw = r15 & 7;

  const bf* asrc[4]; bf* alds[4];
  const bf* bsrc[2]; bf* blds[2];
#pragma unroll
  for (int u = 0; u < 4; ++u) {
    const int sidx = u * 256 + t, row = sidx >> 3, seg = sidx & 7;
    asrc[u] = A + (m0 + row) * K + seg * 8;
    alds[u] = As + row * 64 + ((seg ^ (row & 7)) * 8);
  }
#pragma unroll
  for (int u = 0; u < 2; ++u) {
    const int sidx = u * 256 + t, row = sidx >> 3, seg = sidx & 7;
    bsrc[u] = W + (n0 + row) * K + seg * 8;
    blds[u] = Bs + row * 64 + ((seg ^ (row & 7)) * 8);
  }

  f32x4 acc[4][2] = {};

  auto compute = [&]() {
#pragma unroll
    for (int kk = 0; kk < 2; ++kk) {
      const int sa = (kk * 4 + q4) ^ sw;
      bf16x8 af[4], bfr[2];
#pragma unroll
      for (int i = 0; i < 4; ++i)
        af[i] = *(const bf16x8*)(As + (wm * 64 + i * 16 + r15) * 64 + sa * 8);
#pragma unroll
      for (int j = 0; j < 2; ++j)
        bfr[j] = *(const bf16x8*)(Bs + (wn * 32 + j * 16 + r15) * 64 + sa * 8);
#pragma unroll
      for (int mi = 0; mi < 4; ++mi)
#pragma unroll
        for (int ni = 0; ni < 2; ++ni)
          acc[mi][ni] = __builtin_amdgcn_mfma_f32_16x16x32_bf16(af[mi], bfr[ni], acc[mi][ni], 0, 0, 0);
    }
  };

  {
    bf16x8 ra[4], rb[2];
#pragma unroll
    for (int u = 0; u < 4; ++u) ra[u] = *(const bf16x8*)(asrc[u]);
#pragma unroll
    for (int u = 0; u < 2; ++u) rb[u] = *(const bf16x8*)(bsrc[u]);
#pragma unroll
    for (int u = 0; u < 4; ++u) *(bf16x8*)alds[u] = ra[u];
#pragma unroll
    for (int u = 0; u < 2; ++u) *(bf16x8*)blds[u] = rb[u];
  }
  __syncthreads();
#pragma unroll 1
  for (int k0 = 64; k0 < K; k0 += 64) {
    bf16x8 ra[4], rb[2];
#pragma unroll
    for (int u = 0; u < 4; ++u) ra[u] = *(const bf16x8*)(asrc[u] + k0);
#pragma unroll
    for (int u = 0; u < 2; ++u) rb[u] = *(const bf16x8*)(bsrc[u] + k0);
    compute();
    __syncthreads();
#pragma unroll
    for (int u = 0; u < 4; ++u) *(bf16x8*)alds[u] = ra[u];
#pragma unroll
    for (int u = 0; u < 2; ++u) *(bf16x8*)blds[u] = rb[u];
    __syncthreads();
  }
  compute();

#pragma unroll
  for (int ni = 0; ni < 2; ++ni) {
    const int n = (int)n0 + wn * 32 + ni * 16 + r15;
    const float bv = bias[n];
#pragma unroll
    for (int mi = 0; mi < 4; ++mi)
#pragma unroll
      for (int r = 0; r < 4; ++r) {
        const size_t m = m0 + wm * 64 + mi * 16 + q4 * 4 + r;
        H[m * N + n] = f2b(tanhf(acc[mi][ni][r] + bv));
      }
  }
}

// ---------------------------------------------------------------- fwd3 (out)
__global__ __launch_bounds__(256) void fwd3_k(const bf* __restrict__ h2,
                                              const bf* __restrict__ W3b,
                                              const float* __restrict__ b3,
                                              float* __restrict__ out) {
  __shared__ __align__(16) bf hs[8 * 1024];
  const int t = threadIdx.x;
  const size_t bb = (size_t)blockIdx.x * 8;
  const uint4* src = (const uint4*)(h2 + bb * 1024);
  uint4* dv = (uint4*)hs;
#pragma unroll
  for (int j = 0; j < 4; ++j) dv[j * 256 + t] = src[j * 256 + t];
  __syncthreads();
  const int i = t & 31, bl = t >> 5;
  const bf2* hr = (const bf2*)(hs + bl * 1024);
  const bf2* wr = (const bf2*)(W3b + (size_t)i * 1024);
  float s = 0.f;
#pragma unroll 8
  for (int k2 = 0; k2 < 512; ++k2) {
    float2 a = __bfloat1622float2(hr[k2]);
    float2 c = __bfloat1622float2(wr[k2]);
    s += a.x * c.x + a.y * c.y;
  }
  out[(bb + bl) * 32 + i] = s + b3[i];
}

// ---------------------------------------------------------------- t0 build
// T0[(b,i)][q] = (1-h0[b,q]^2)*W0T[i,q], chunk-local rows. Streaming VALU.
__global__ __launch_bounds__(256) void t0_k(const bf* __restrict__ h0c,
                                            const bf* __restrict__ W0T,
                                            bf* __restrict__ T0) {
  const int idx = blockIdx.x * 256 + threadIdx.x;
  const int m = idx >> 6, seg = idx & 63;
  const int b = m >> 5, i = m & 31;
  const bf2* hp = (const bf2*)(h0c + (size_t)b * 1024 + seg * 16);
  const bf2* wp = (const bf2*)(W0T + (size_t)i * 1024 + seg * 16);
  bf2* dp = (bf2*)(T0 + (size_t)m * 1024 + seg * 16);
#pragma unroll
  for (int u = 0; u < 8; ++u) {
    float2 h = __bfloat1622float2(hp[u]);
    float2 w = __bfloat1622float2(wp[u]);
    float2 r;
    r.x = (1.f - h.x * h.x) * w.x;
    r.y = (1.f - h.y * h.y) * w.y;
    dp[u] = __float22bfloat162_rn(r);
  }
}

// ---------------------------------------------------------------- jvp1
// T1[m][n] = (1-h1[b,n]^2)*sum_q T0[m][q]*W1[n,q].
// 256x128 block, 128x64 wave-tile (8x4), BK=32, pitch-40, ping-pong LDS,
// bank-uniform write permutation, register-staged prefetch.
__global__ __launch_bounds__(256, 2) void gemm_jvp1(const bf* __restrict__ T0,
                                                    const bf* __restrict__ W1b,
                                                    const bf* __restrict__ h1c,
                                                    bf* __restrict__ T1) {
  constexpr int K = 1024, N = 1024, P = 40;
  __shared__ __align__(16) bf As[2][256 * P];
  __shared__ __align__(16) bf Bs[2][128 * P];
  const int t = threadIdx.x, l = t & 63, w = t >> 6;
  const int wm = w >> 1, wn = w & 1;
  const int f = blockIdx.x;
  const int n_t = (f >> 3) & 7, m_t = (f & 7) + 8 * (f >> 6);
  const size_t m0 = (size_t)m_t * 256, n0 = (size_t)n_t * 128;
  const int r15 = l & 15, q4 = l >> 4;

  // bank-uniform staging map: phase ph=l>>4 gets rows {x,x+4,x+8,x+12}
  const int ph = l >> 4, jj = l & 15;
  const int srow = w * 16 + (jj & 3) * 4 + ph;   // 0..63 within 64-row group
  const int sseg = jj >> 2;                      // 0..3
  const bf* asrc[4]; int aoff[4];
  const bf* bsrc[2]; int boff[2];
#pragma unroll
  for (int u = 0; u < 4; ++u) {
    const int row = u * 64 + srow;
    asrc[u] = T0 + (m0 + row) * K + sseg * 8;
    aoff[u] = row * P + sseg * 8;
  }
#pragma unroll
  for (int u = 0; u < 2; ++u) {
    const int row = u * 64 + srow;
    bsrc[u] = W1b + (n0 + row) * K + sseg * 8;
    boff[u] = row * P + sseg * 8;
  }

  f32x4 acc[8][4] = {};

  auto compute = [&](const bf* A_, const bf* B_) {
    bf16x8 af[8], bfr[4];
#pragma unroll
    for (int i = 0; i < 8; ++i)
      af[i] = *(const bf16x8*)(A_ + (wm * 128 + i * 16 + r15) * P + q4 * 8);
#pragma unroll
    for (int j = 0; j < 4; ++j)
      bfr[j] = *(const bf16x8*)(B_ + (wn * 64 + j * 16 + r15) * P + q4 * 8);
#pragma unroll
    for (int mi = 0; mi < 8; ++mi)
#pragma unroll
      for (int ni = 0; ni < 4; ++ni)
        acc[mi][ni] = __builtin_amdgcn_mfma_f32_16x16x32_bf16(af[mi], bfr[ni], acc[mi][ni], 0, 0, 0);
  };

  const bf *Ard = &As[0][0], *Brd = &Bs[0][0];
  bf *Awr = &As[1][0], *Bwr = &Bs[1][0];

  {  // prologue: stage k=0 into buf0
    bf16x8 ra[4], rb[2];
#pragma unroll
    for (int u = 0; u < 4; ++u) ra[u] = *(const bf16x8*)(asrc[u]);
#pragma unroll
    for (int u = 0; u < 2; ++u) rb[u] = *(const bf16x8*)(bsrc[u]);
#pragma unroll
    for (int u = 0; u < 4; ++u) *(bf16x8*)(&As[0][0] + aoff[u]) = ra[u];
#pragma unroll
    for (int u = 0; u < 2; ++u) *(bf16x8*)(&Bs[0][0] + boff[u]) = rb[u];
  }
  __syncthreads();
#pragma unroll 1
  for (int k0 = 32; k0 < K; k0 += 32) {
    bf16x8 ra[4], rb[2];
#pragma unroll
    for (int u = 0; u < 4; ++u) ra[u] = *(const bf16x8*)(asrc[u] + k0);
#pragma unroll
    for (int u = 0; u < 2; ++u) rb[u] = *(const bf16x8*)(bsrc[u] + k0);
    compute(Ard, Brd);
#pragma unroll
    for (int u = 0; u < 4; ++u) *(bf16x8*)(Awr + aoff[u]) = ra[u];
#pragma unroll
    for (int u = 0; u < 2; ++u) *(bf16x8*)(Bwr + boff[u]) = rb[u];
    __syncthreads();
    const bf* ta = Ard; Ard = Awr; Awr = (bf*)ta;
    const bf* tb = Brd; Brd = Bwr; Bwr = (bf*)tb;
  }
  compute(Ard, Brd);

  const int bbase = (int)((m0 + wm * 128) >> 5);  // 4 samples per wave
#pragma unroll
  for (int ni = 0; ni < 4; ++ni) {
    const int n = (int)n0 + wn * 64 + ni * 16 + r15;
    float a1v[4];
#pragma unroll
    for (int s = 0; s < 4; ++s) {
      const float hv = b2f(h1c[(size_t)(bbase + s) * 1024 + n]);
      a1v[s] = 1.f - hv * hv;
    }
#pragma unroll
    for (int mi = 0; mi < 8; ++mi)
#pragma unroll
      for (int r = 0; r < 4; ++r) {
        const size_t m = m0 + wm * 128 + mi * 16 + q4 * 4 + r;
        T1[m * N + n] = f2b(a1v[mi >> 1] * acc[mi][ni][r]);
      }
  }
}

// ---------------------------------------------------------------- jvp2
// U2 = W2 @ T1; trace[b] -= sum_{p,i} W3[i,p]*(1-h2[b,p]^2)*U2[p,(b,i)]
__global__ __launch_bounds__(256, 2) void gemm_jvp2(const bf* __restrict__ T1,
                                                    const bf* __restrict__ W2b,
                                                    const bf* __restrict__ W3b,
                                                    const bf* __restrict__ h2c,
                                                    float* __restrict__ trace) {
  constexpr int K = 1024, P = 40;
  __shared__ __align__(16) bf As[2][256 * P];
  __shared__ __align__(16) bf Bs[2][128 * P];
  const int t = threadIdx.x, l = t & 63, w = t >> 6;
  const int wm = w >> 1, wn = w & 1;
  const int f = blockIdx.x;
  const int n_t = (f >> 3) & 7, m_t = (f & 7) + 8 * (f >> 6);
  const size_t m0 = (size_t)m_t * 256, n0 = (size_t)n_t * 128;
  const int r15 = l & 15, q4 = l >> 4;

  const int ph = l >> 4, jj = l & 15;
  const int srow = w * 16 + (jj & 3) * 4 + ph;
  const int sseg = jj >> 2;
  const bf* asrc[4]; int aoff[4];
  const bf* bsrc[2]; int boff[2];
#pragma unroll
  for (int u = 0; u < 4; ++u) {
    const int row = u * 64 + srow;
    asrc[u] = T1 + (m0 + row) * K + sseg * 8;
    aoff[u] = row * P + sseg * 8;
  }
#pragma unroll
  for (int u = 0; u < 2; ++u) {
    const int row = u * 64 + srow;
    bsrc[u] = W2b + (n0 + row) * K + sseg * 8;
    boff[u] = row * P + sseg * 8;
  }

  f32x4 acc[8][4] = {};

  auto compute = [&](const bf* A_, const bf* B_) {
    bf16x8 af[8], bfr[4];
#pragma unroll
    for (int i = 0; i < 8; ++i)
      af[i] = *(const bf16x8*)(A_ + (wm * 128 + i * 16 + r15) * P + q4 * 8);
#pragma unroll
    for (int j = 0; j < 4; ++j)
      bfr[j] = *(const bf16x8*)(B_ + (wn * 64 + j * 16 + r15) * P + q4 * 8);
#pragma unroll
    for (int mi = 0; mi < 8; ++mi)
#pragma unroll
      for (int ni = 0; ni < 4; ++ni)
        acc[mi][ni] = __builtin_amdgcn_mfma_f32_16x16x32_bf16(af[mi], bfr[ni], acc[mi][ni], 0, 0, 0);
  };

  const bf *Ard = &As[0][0], *Brd = &Bs[0][0];
  bf *Awr = &As[1][0], *Bwr = &Bs[1][0];

  {  // prologue
    bf16x8 ra[4], rb[2];
#pragma unroll
    for (int u = 0; u < 4; ++u) ra[u] = *(const bf16x8*)(asrc[u]);
#pragma unroll
    for (int u = 0; u < 2; ++u) rb[u] = *(const bf16x8*)(bsrc[u]);
#pragma unroll
    for (int u = 0; u < 4; ++u) *(bf16x8*)(&As[0][0] + aoff[u]) = ra[u];
#pragma unroll
    for (int u = 0; u < 2; ++u) *(bf16x8*)(&Bs[0][0] + boff[u]) = rb[u];
  }
  __syncthreads();
#pragma unroll 1
  for (int k0 = 32; k0 < K; k0 += 32) {
    bf16x8 ra[4], rb[2];
#pragma unroll
    for (int u = 0; u < 4; ++u) ra[u] = *(const bf16x8*)(asrc[u] + k0);
#pragma unroll
    for (int u = 0; u < 2; ++u) rb[u] = *(const bf16x8*)(bsrc[u] + k0);
    compute(Ard, Brd);
#pragma unroll
    for (int u = 0; u < 4; ++u) *(bf16x8*)(Awr + aoff[u]) = ra[u];
#pragma unroll
    for (int u = 0; u < 2; ++u) *(bf16x8*)(Bwr + boff[u]) = rb[u];
    __syncthreads();
    const bf* ta = Ard; Ard = Awr; Awr = (bf*)ta;
    const bf* tb = Brd; Brd = Bwr; Bwr = (bf*)tb;
  }
  compute(Ard, Brd);

  const int bbase = (int)((m0 + wm * 128) >> 5);  // 4 samples per wave
  float part[4] = {0.f, 0.f, 0.f, 0.f};
#pragma unroll
  for (int ni = 0; ni < 4; ++ni) {
    const int n = (int)n0 + wn * 64 + ni * 16 + r15;  // = p
    float a2v[4];
#pragma unroll
    for (int s = 0; s < 4; ++s) {
      const float hv = b2f(h2c[(size_t)(bbase + s) * 1024 + n]);
      a2v[s] = 1.f - hv * hv;
    }
#pragma unroll
    for (int mi = 0; mi < 8; ++mi) {
      const int isel = mi >> 1;
#pragma unroll
      for (int r = 0; r < 4; ++r) {
        const int mm = wm * 128 + mi * 16 + q4 * 4 + r;  // i = mm & 31
        part[isel] += b2f(W3b[(size_t)(mm & 31) * 1024 + n]) * a2v[isel] * acc[mi][ni][r];
      }
    }
  }
#pragma unroll
  for (int off = 32; off > 0; off >>= 1) {
#pragma unroll
    for (int s = 0; s < 4; ++s) part[s] += __shfl_down(part[s], off);
  }
  if (l == 0) {
#pragma unroll
    for (int s = 0; s < 4; ++s) atomicAdd(trace + bbase + s, -part[s]);
  }
}

// ---------------------------------------------------------------- divv
__global__ void divv_k(const float* __restrict__ tr, float* __restrict__ dv) {
  const int b = blockIdx.x * 256 + threadIdx.x;
  dv[b] = tr[b];
}

// ================================================================ launch
extern "C" void kernel_launch(void* const* d_in, const int* in_sizes, int n_in,
                              void* d_out, int out_size, void* d_ws, size_t ws_size,
                              hipStream_t stream) {
  const float* tin = (const float*)d_in[0];
  const float* z   = (const float*)d_in[1];
  const float* W0  = (const float*)d_in[2];
  const float* b0  = (const float*)d_in[3];
  const float* W1  = (const float*)d_in[4];
  const float* b1  = (const float*)d_in[5];
  const float* W2  = (const float*)d_in[6];
  const float* b2  = (const float*)d_in[7];
  const float* W3  = (const float*)d_in[8];
  const float* b3  = (const float*)d_in[9];
  float* out = (float*)d_out;
  (void)in_sizes; (void)n_in; (void)out_size;

  char* ws = (char*)d_ws;
  size_t off = 0;
  auto take = [&](size_t bytes) {
    char* p = ws + off;
    off = (off + bytes + 255) & ~(size_t)255;
    return p;
  };
  bf* h0   = (bf*)take((size_t)4096 * 1024 * 2);   // 8 MB
  bf* h1   = (bf*)take((size_t)4096 * 1024 * 2);   // 8 MB
  bf* h2   = (bf*)take((size_t)4096 * 1024 * 2);   // 8 MB
  bf* W0T  = (bf*)take((size_t)32 * 1024 * 2);     // 64 KB
  bf* W1b  = (bf*)take((size_t)1024 * 1024 * 2);   // 2 MB
  bf* W2b  = (bf*)take((size_t)1024 * 1024 * 2);   // 2 MB
  bf* W3b  = (bf*)take((size_t)32 * 1024 * 2);     // 64 KB
  float* tr = (float*)take((size_t)4096 * 4);      // 16 KB
  // chunk size: T0 + T1, each NB*32*1024*2 bytes; NB multiple of 8
  const size_t avail = (ws_size > off) ? (ws_size - off) : 0;
  int NB = 2048;
  while (NB > 256 && 2 * (size_t)NB * 65536 > avail) NB >>= 1;
  bf* T0 = (bf*)take((size_t)NB * 65536);
  bf* T1 = (bf*)take((size_t)NB * 65536);

  hipMemsetAsync(tr, 0, 4096 * sizeof(float), stream);
  conv_k<<<dim3(1024), dim3(256), 0, stream>>>(W1, W1b, 262144);
  conv_k<<<dim3(1024), dim3(256), 0, stream>>>(W2, W2b, 262144);
  conv_k<<<dim3(32),   dim3(256), 0, stream>>>(W3, W3b, 8192);
  w0t_k<<<dim3(128), dim3(256), 0, stream>>>(W0, W0T);
  fwd0_k<<<dim3(128), dim3(256), 0, stream>>>(z, tin, W0, b0, h0);
  gemm_fwd<<<dim3(512), dim3(256), 0, stream>>>(h0, W1b, b1, h1);
  gemm_fwd<<<dim3(512), dim3(256), 0, stream>>>(h1, W2b, b2, h2);
  fwd3_k<<<dim3(512), dim3(256), 0, stream>>>(h2, W3b, b3, out);
  for (int cb = 0; cb < 4096; cb += NB) {
    t0_k<<<dim3(NB * 8), dim3(256), 0, stream>>>(h0 + (size_t)cb * 1024, W0T, T0);
    gemm_jvp1<<<dim3(NB), dim3(256), 0, stream>>>(
        T0, W1b, h1 + (size_t)cb * 1024, T1);
    gemm_jvp2<<<dim3(NB), dim3(256), 0, stream>>>(
        T1, W2b, W3b, h2 + (size_t)cb * 1024, tr + cb);
  }
  divv_k<<<dim3(16), dim3(256), 0, stream>>>(tr, out + 131072);
}

// Round 9
// 851.942 us; speedup vs baseline: 1.2417x; 1.2417x over previous
//
#include <hip/hip_runtime.h>
#include <hip/hip_bf16.h>
#include <stdint.h>

// CNF step: 4-layer tanh MLP (33->1024->1024->1024->32) forward + exact
// Jacobian trace via 32 forward-mode tangents. B=4096, H=1024, D=32.
// f32 in/out; bf16 MFMA internally.
//
// R9: synthesis of measured winners.
//  - R7's 256x128 block / 128x64 wave-tile (best FLOP per LDS byte; VALUBusy
//    15%) BUT R7's pitch-40 LDS reads measured 1.26e7 bank conflicts (R8
//    proved it's the reads: write-map change left the count identical).
//  - R6's XOR-swizzle pitch-64 layout measured ZERO conflicts: each row =
//    128B = one full bank sweep; any 8-lane group covers all 32 banks once
//    (reads AND writes). Adopt it here with BK=64.
//  - R6's two-barrier register-staged loop with COMPILE-TIME LDS bases
//    (R8's ping-pong pointer swap defeated static addressing: MfmaUtil
//    31->24%). Global->VGPR prefetch of tile k+1 issued before compute(k).

using bf  = __hip_bfloat16;
using bf2 = __hip_bfloat162;
typedef __attribute__((ext_vector_type(8))) short bf16x8;   // 8 bf16 = 4 VGPRs
typedef __attribute__((ext_vector_type(4))) float f32x4;    // C/D frag

__device__ __forceinline__ float b2f(bf x)    { return __bfloat162float(x); }
__device__ __forceinline__ bf    f2b(float x) { return __float2bfloat16(x); }

// ------------------------------------------------------- f32 -> bf16 convert
__global__ __launch_bounds__(256) void conv_k(const float* __restrict__ src,
                                              bf* __restrict__ dst, int n4) {
  const int i = blockIdx.x * 256 + threadIdx.x;
  if (i >= n4) return;
  float4 v = ((const float4*)src)[i];
  bf2* d = (bf2*)(dst + (size_t)i * 4);
  d[0] = __float22bfloat162_rn(make_float2(v.x, v.y));
  d[1] = __float22bfloat162_rn(make_float2(v.z, v.w));
}

// ------------------------------------------------- W0T bf16 (32x1024) from f32
__global__ void w0t_k(const float* __restrict__ W0, bf* __restrict__ W0T) {
  const int idx = blockIdx.x * 256 + threadIdx.x;  // 32768 total
  const int i = idx >> 10, q = idx & 1023;
  W0T[idx] = f2b(W0[q * 33 + i]);
}

// ---------------------------------------------------------------- fwd0
__global__ __launch_bounds__(256) void fwd0_k(const float* __restrict__ z,
                                              const float* __restrict__ tin,
                                              const float* __restrict__ W0,
                                              const float* __restrict__ b0,
                                              bf* __restrict__ h0) {
  __shared__ float zs[32 * 33];  // [s][k], k=32 is t
  const int t = threadIdx.x;
  const int s0 = blockIdx.x * 32;
  for (int j = t; j < 1024; j += 256) {
    const int s = j >> 5, k = j & 31;
    zs[s * 33 + k] = z[(size_t)(s0 + s) * 32 + k];
  }
  if (t < 32) zs[t * 33 + 32] = tin[0];
  __syncthreads();
#pragma unroll 1
  for (int rep = 0; rep < 4; ++rep) {
    const int hh = rep * 256 + t;
    const float* wr = W0 + (size_t)hh * 33;
    float wv[33];
#pragma unroll
    for (int k = 0; k < 33; ++k) wv[k] = wr[k];
    const float bv = b0[hh];
#pragma unroll 1
    for (int s = 0; s < 32; ++s) {
      float acc = bv;
#pragma unroll
      for (int k = 0; k < 33; ++k) acc += wv[k] * zs[s * 33 + k];
      h0[(size_t)(s0 + s) * 1024 + hh] = f2b(tanhf(acc));
    }
  }
}

// ---------------------------------------------------------------- fwd GEMM
// H[m][n] = tanh(sum_k A[m][k]*W[n][k] + bias[n]); M=4096, N=K=1024.
// 128x64 tile, BK=64, register-staged, XOR swizzle (R6 core, 0 conflicts).
__global__ __launch_bounds__(256) void gemm_fwd(const bf* __restrict__ A,
                                                const bf* __restrict__ W,
                                                const float* __restrict__ bias,
                                                bf* __restrict__ H) {
  constexpr int K = 1024, N = 1024;
  __shared__ __align__(16) bf As[128 * 64];
  __shared__ __align__(16) bf Bs[64 * 64];
  const int t = threadIdx.x, l = t & 63, w = t >> 6;
  const int wm = w >> 1, wn = w & 1;
  const int f = blockIdx.x;
  const int n_t = (f >> 3) & 15, m_t = (f & 7) + 8 * (f >> 7);
  const size_t m0 = (size_t)m_t * 128, n0 = (size_t)n_t * 64;
  const int r15 = l & 15, q4 = l >> 4, sw = r15 & 7;

  const bf* asrc[4]; bf* alds[4];
  const bf* bsrc[2]; bf* blds[2];
#pragma unroll
  for (int u = 0; u < 4; ++u) {
    const int sidx = u * 256 + t, row = sidx >> 3, seg = sidx & 7;
    asrc[u] = A + (m0 + row) * K + seg * 8;
    alds[u] = As + row * 64 + ((seg ^ (row & 7)) * 8);
  }
#pragma unroll
  for (int u = 0; u < 2; ++u) {
    const int sidx = u * 256 + t, row = sidx >> 3, seg = sidx & 7;
    bsrc[u] = W + (n0 + row) * K + seg * 8;
    blds[u] = Bs + row * 64 + ((seg ^ (row & 7)) * 8);
  }

  f32x4 acc[4][2] = {};

  auto compute = [&]() {
#pragma unroll
    for (int kk = 0; kk < 2; ++kk) {
      const int sa = (kk * 4 + q4) ^ sw;
      bf16x8 af[4], bfr[2];
#pragma unroll
      for (int i = 0; i < 4; ++i)
        af[i] = *(const bf16x8*)(As + (wm * 64 + i * 16 + r15) * 64 + sa * 8);
#pragma unroll
      for (int j = 0; j < 2; ++j)
        bfr[j] = *(const bf16x8*)(Bs + (wn * 32 + j * 16 + r15) * 64 + sa * 8);
#pragma unroll
      for (int mi = 0; mi < 4; ++mi)
#pragma unroll
        for (int ni = 0; ni < 2; ++ni)
          acc[mi][ni] = __builtin_amdgcn_mfma_f32_16x16x32_bf16(af[mi], bfr[ni], acc[mi][ni], 0, 0, 0);
    }
  };

  {
    bf16x8 ra[4], rb[2];
#pragma unroll
    for (int u = 0; u < 4; ++u) ra[u] = *(const bf16x8*)(asrc[u]);
#pragma unroll
    for (int u = 0; u < 2; ++u) rb[u] = *(const bf16x8*)(bsrc[u]);
#pragma unroll
    for (int u = 0; u < 4; ++u) *(bf16x8*)alds[u] = ra[u];
#pragma unroll
    for (int u = 0; u < 2; ++u) *(bf16x8*)blds[u] = rb[u];
  }
  __syncthreads();
#pragma unroll 1
  for (int k0 = 64; k0 < K; k0 += 64) {
    bf16x8 ra[4], rb[2];
#pragma unroll
    for (int u = 0; u < 4; ++u) ra[u] = *(const bf16x8*)(asrc[u] + k0);
#pragma unroll
    for (int u = 0; u < 2; ++u) rb[u] = *(const bf16x8*)(bsrc[u] + k0);
    compute();
    __syncthreads();
#pragma unroll
    for (int u = 0; u < 4; ++u) *(bf16x8*)alds[u] = ra[u];
#pragma unroll
    for (int u = 0; u < 2; ++u) *(bf16x8*)blds[u] = rb[u];
    __syncthreads();
  }
  compute();

#pragma unroll
  for (int ni = 0; ni < 2; ++ni) {
    const int n = (int)n0 + wn * 32 + ni * 16 + r15;
    const float bv = bias[n];
#pragma unroll
    for (int mi = 0; mi < 4; ++mi)
#pragma unroll
      for (int r = 0; r < 4; ++r) {
        const size_t m = m0 + wm * 64 + mi * 16 + q4 * 4 + r;
        H[m * N + n] = f2b(tanhf(acc[mi][ni][r] + bv));
      }
  }
}

// ---------------------------------------------------------------- fwd3 (out)
__global__ __launch_bounds__(256) void fwd3_k(const bf* __restrict__ h2,
                                              const bf* __restrict__ W3b,
                                              const float* __restrict__ b3,
                                              float* __restrict__ out) {
  __shared__ __align__(16) bf hs[8 * 1024];
  const int t = threadIdx.x;
  const size_t bb = (size_t)blockIdx.x * 8;
  const uint4* src = (const uint4*)(h2 + bb * 1024);
  uint4* dv = (uint4*)hs;
#pragma unroll
  for (int j = 0; j < 4; ++j) dv[j * 256 + t] = src[j * 256 + t];
  __syncthreads();
  const int i = t & 31, bl = t >> 5;
  const bf2* hr = (const bf2*)(hs + bl * 1024);
  const bf2* wr = (const bf2*)(W3b + (size_t)i * 1024);
  float s = 0.f;
#pragma unroll 8
  for (int k2 = 0; k2 < 512; ++k2) {
    float2 a = __bfloat1622float2(hr[k2]);
    float2 c = __bfloat1622float2(wr[k2]);
    s += a.x * c.x + a.y * c.y;
  }
  out[(bb + bl) * 32 + i] = s + b3[i];
}

// ---------------------------------------------------------------- t0 build
// T0[(b,i)][q] = (1-h0[b,q]^2)*W0T[i,q], chunk-local rows. Streaming VALU.
__global__ __launch_bounds__(256) void t0_k(const bf* __restrict__ h0c,
                                            const bf* __restrict__ W0T,
                                            bf* __restrict__ T0) {
  const int idx = blockIdx.x * 256 + threadIdx.x;
  const int m = idx >> 6, seg = idx & 63;
  const int b = m >> 5, i = m & 31;
  const bf2* hp = (const bf2*)(h0c + (size_t)b * 1024 + seg * 16);
  const bf2* wp = (const bf2*)(W0T + (size_t)i * 1024 + seg * 16);
  bf2* dp = (bf2*)(T0 + (size_t)m * 1024 + seg * 16);
#pragma unroll
  for (int u = 0; u < 8; ++u) {
    float2 h = __bfloat1622float2(hp[u]);
    float2 w = __bfloat1622float2(wp[u]);
    float2 r;
    r.x = (1.f - h.x * h.x) * w.x;
    r.y = (1.f - h.y * h.y) * w.y;
    dp[u] = __float22bfloat162_rn(r);
  }
}

// ---------------------------------------------------------------- jvp1
// T1[m][n] = (1-h1[b,n]^2)*sum_q T0[m][q]*W1[n,q].
// 256x128 block, 128x64 wave-tile (8x4), BK=64, XOR-swizzle pitch-64 LDS
// (conflict-free), two-barrier register-staged pipeline, static LDS bases.
__global__ __launch_bounds__(256, 2) void gemm_jvp1(const bf* __restrict__ T0,
                                                    const bf* __restrict__ W1b,
                                                    const bf* __restrict__ h1c,
                                                    bf* __restrict__ T1) {
  constexpr int K = 1024, N = 1024;
  __shared__ __align__(16) bf As[256 * 64];   // 32 KB
  __shared__ __align__(16) bf Bs[128 * 64];   // 16 KB
  const int t = threadIdx.x, l = t & 63, w = t >> 6;
  const int wm = w >> 1, wn = w & 1;
  const int f = blockIdx.x;
  const int n_t = (f >> 3) & 7, m_t = (f & 7) + 8 * (f >> 6);
  const size_t m0 = (size_t)m_t * 256, n0 = (size_t)n_t * 128;
  const int r15 = l & 15, q4 = l >> 4, sw = r15 & 7;

  const bf* asrc[8]; int aoff[8];
  const bf* bsrc[4]; int boff[4];
#pragma unroll
  for (int u = 0; u < 8; ++u) {
    const int sidx = u * 256 + t, row = sidx >> 3, seg = sidx & 7;
    asrc[u] = T0 + (m0 + row) * K + seg * 8;
    aoff[u] = row * 64 + ((seg ^ (row & 7)) * 8);
  }
#pragma unroll
  for (int u = 0; u < 4; ++u) {
    const int sidx = u * 256 + t, row = sidx >> 3, seg = sidx & 7;
    bsrc[u] = W1b + (n0 + row) * K + seg * 8;
    boff[u] = row * 64 + ((seg ^ (row & 7)) * 8);
  }

  f32x4 acc[8][4] = {};

  auto compute = [&]() {
#pragma unroll
    for (int kk = 0; kk < 2; ++kk) {
      const int sa = (kk * 4 + q4) ^ sw;
      bf16x8 af[8], bfr[4];
#pragma unroll
      for (int i = 0; i < 8; ++i)
        af[i] = *(const bf16x8*)(As + (wm * 128 + i * 16 + r15) * 64 + sa * 8);
#pragma unroll
      for (int j = 0; j < 4; ++j)
        bfr[j] = *(const bf16x8*)(Bs + (wn * 64 + j * 16 + r15) * 64 + sa * 8);
#pragma unroll
      for (int mi = 0; mi < 8; ++mi)
#pragma unroll
        for (int ni = 0; ni < 4; ++ni)
          acc[mi][ni] = __builtin_amdgcn_mfma_f32_16x16x32_bf16(af[mi], bfr[ni], acc[mi][ni], 0, 0, 0);
    }
  };

  {  // prologue: stage k=0
    bf16x8 ra[8], rb[4];
#pragma unroll
    for (int u = 0; u < 8; ++u) ra[u] = *(const bf16x8*)(asrc[u]);
#pragma unroll
    for (int u = 0; u < 4; ++u) rb[u] = *(const bf16x8*)(bsrc[u]);
#pragma unroll
    for (int u = 0; u < 8; ++u) *(bf16x8*)(As + aoff[u]) = ra[u];
#pragma unroll
    for (int u = 0; u < 4; ++u) *(bf16x8*)(Bs + boff[u]) = rb[u];
  }
  __syncthreads();
#pragma unroll 1
  for (int k0 = 64; k0 < K; k0 += 64) {
    bf16x8 ra[8], rb[4];
#pragma unroll
    for (int u = 0; u < 8; ++u) ra[u] = *(const bf16x8*)(asrc[u] + k0);
#pragma unroll
    for (int u = 0; u < 4; ++u) rb[u] = *(const bf16x8*)(bsrc[u] + k0);
    compute();
    __syncthreads();
#pragma unroll
    for (int u = 0; u < 8; ++u) *(bf16x8*)(As + aoff[u]) = ra[u];
#pragma unroll
    for (int u = 0; u < 4; ++u) *(bf16x8*)(Bs + boff[u]) = rb[u];
    __syncthreads();
  }
  compute();

  const int bbase = (int)((m0 + wm * 128) >> 5);  // 4 samples per wave
#pragma unroll
  for (int ni = 0; ni < 4; ++ni) {
    const int n = (int)n0 + wn * 64 + ni * 16 + r15;
    float a1v[4];
#pragma unroll
    for (int s = 0; s < 4; ++s) {
      const float hv = b2f(h1c[(size_t)(bbase + s) * 1024 + n]);
      a1v[s] = 1.f - hv * hv;
    }
#pragma unroll
    for (int mi = 0; mi < 8; ++mi)
#pragma unroll
      for (int r = 0; r < 4; ++r) {
        const size_t m = m0 + wm * 128 + mi * 16 + q4 * 4 + r;
        T1[m * N + n] = f2b(a1v[mi >> 1] * acc[mi][ni][r]);
      }
  }
}

// ---------------------------------------------------------------- jvp2
// U2 = W2 @ T1; trace[b] -= sum_{p,i} W3[i,p]*(1-h2[b,p]^2)*U2[p,(b,i)]
__global__ __launch_bounds__(256, 2) void gemm_jvp2(const bf* __restrict__ T1,
                                                    const bf* __restrict__ W2b,
                                                    const bf* __restrict__ W3b,
                                                    const bf* __restrict__ h2c,
                                                    float* __restrict__ trace) {
  constexpr int K = 1024;
  __shared__ __align__(16) bf As[256 * 64];
  __shared__ __align__(16) bf Bs[128 * 64];
  const int t = threadIdx.x, l = t & 63, w = t >> 6;
  const int wm = w >> 1, wn = w & 1;
  const int f = blockIdx.x;
  const int n_t = (f >> 3) & 7, m_t = (f & 7) + 8 * (f >> 6);
  const size_t m0 = (size_t)m_t * 256, n0 = (size_t)n_t * 128;
  const int r15 = l & 15, q4 = l >> 4, sw = r15 & 7;

  const bf* asrc[8]; int aoff[8];
  const bf* bsrc[4]; int boff[4];
#pragma unroll
  for (int u = 0; u < 8; ++u) {
    const int sidx = u * 256 + t, row = sidx >> 3, seg = sidx & 7;
    asrc[u] = T1 + (m0 + row) * K + seg * 8;
    aoff[u] = row * 64 + ((seg ^ (row & 7)) * 8);
  }
#pragma unroll
  for (int u = 0; u < 4; ++u) {
    const int sidx = u * 256 + t, row = sidx >> 3, seg = sidx & 7;
    bsrc[u] = W2b + (n0 + row) * K + seg * 8;
    boff[u] = row * 64 + ((seg ^ (row & 7)) * 8);
  }

  f32x4 acc[8][4] = {};

  auto compute = [&]() {
#pragma unroll
    for (int kk = 0; kk < 2; ++kk) {
      const int sa = (kk * 4 + q4) ^ sw;
      bf16x8 af[8], bfr[4];
#pragma unroll
      for (int i = 0; i < 8; ++i)
        af[i] = *(const bf16x8*)(As + (wm * 128 + i * 16 + r15) * 64 + sa * 8);
#pragma unroll
      for (int j = 0; j < 4; ++j)
        bfr[j] = *(const bf16x8*)(Bs + (wn * 64 + j * 16 + r15) * 64 + sa * 8);
#pragma unroll
      for (int mi = 0; mi < 8; ++mi)
#pragma unroll
        for (int ni = 0; ni < 4; ++ni)
          acc[mi][ni] = __builtin_amdgcn_mfma_f32_16x16x32_bf16(af[mi], bfr[ni], acc[mi][ni], 0, 0, 0);
    }
  };

  {  // prologue
    bf16x8 ra[8], rb[4];
#pragma unroll
    for (int u = 0; u < 8; ++u) ra[u] = *(const bf16x8*)(asrc[u]);
#pragma unroll
    for (int u = 0; u < 4; ++u) rb[u] = *(const bf16x8*)(bsrc[u]);
#pragma unroll
    for (int u = 0; u < 8; ++u) *(bf16x8*)(As + aoff[u]) = ra[u];
#pragma unroll
    for (int u = 0; u < 4; ++u) *(bf16x8*)(Bs + boff[u]) = rb[u];
  }
  __syncthreads();
#pragma unroll 1
  for (int k0 = 64; k0 < K; k0 += 64) {
    bf16x8 ra[8], rb[4];
#pragma unroll
    for (int u = 0; u < 8; ++u) ra[u] = *(const bf16x8*)(asrc[u] + k0);
#pragma unroll
    for (int u = 0; u < 4; ++u) rb[u] = *(const bf16x8*)(bsrc[u] + k0);
    compute();
    __syncthreads();
#pragma unroll
    for (int u = 0; u < 8; ++u) *(bf16x8*)(As + aoff[u]) = ra[u];
#pragma unroll
    for (int u = 0; u < 4; ++u) *(bf16x8*)(Bs + boff[u]) = rb[u];
    __syncthreads();
  }
  compute();

  const int bbase = (int)((m0 + wm * 128) >> 5);  // 4 samples per wave
  float part[4] = {0.f, 0.f, 0.f, 0.f};
#pragma unroll
  for (int ni = 0; ni < 4; ++ni) {
    const int n = (int)n0 + wn * 64 + ni * 16 + r15;  // = p
    float a2v[4];
#pragma unroll
    for (int s = 0; s < 4; ++s) {
      const float hv = b2f(h2c[(size_t)(bbase + s) * 1024 + n]);
      a2v[s] = 1.f - hv * hv;
    }
#pragma unroll
    for (int mi = 0; mi < 8; ++mi) {
      const int isel = mi >> 1;
#pragma unroll
      for (int r = 0; r < 4; ++r) {
        const int mm = wm * 128 + mi * 16 + q4 * 4 + r;  // i = mm & 31
        part[isel] += b2f(W3b[(size_t)(mm & 31) * 1024 + n]) * a2v[isel] * acc[mi][ni][r];
      }
    }
  }
#pragma unroll
  for (int off = 32; off > 0; off >>= 1) {
#pragma unroll
    for (int s = 0; s < 4; ++s) part[s] += __shfl_down(part[s], off);
  }
  if (l == 0) {
#pragma unroll
    for (int s = 0; s < 4; ++s) atomicAdd(trace + bbase + s, -part[s]);
  }
}

// ---------------------------------------------------------------- divv
__global__ void divv_k(const float* __restrict__ tr, float* __restrict__ dv) {
  const int b = blockIdx.x * 256 + threadIdx.x;
  dv[b] = tr[b];
}

// ================================================================ launch
extern "C" void kernel_launch(void* const* d_in, const int* in_sizes, int n_in,
                              void* d_out, int out_size, void* d_ws, size_t ws_size,
                              hipStream_t stream) {
  const float* tin = (const float*)d_in[0];
  const float* z   = (const float*)d_in[1];
  const float* W0  = (const float*)d_in[2];
  const float* b0  = (const float*)d_in[3];
  const float* W1  = (const float*)d_in[4];
  const float* b1  = (const float*)d_in[5];
  const float* W2  = (const float*)d_in[6];
  const float* b2  = (const float*)d_in[7];
  const float* W3  = (const float*)d_in[8];
  const float* b3  = (const float*)d_in[9];
  float* out = (float*)d_out;
  (void)in_sizes; (void)n_in; (void)out_size;

  char* ws = (char*)d_ws;
  size_t off = 0;
  auto take = [&](size_t bytes) {
    char* p = ws + off;
    off = (off + bytes + 255) & ~(size_t)255;
    return p;
  };
  bf* h0   = (bf*)take((size_t)4096 * 1024 * 2);   // 8 MB
  bf* h1   = (bf*)take((size_t)4096 * 1024 * 2);   // 8 MB
  bf* h2   = (bf*)take((size_t)4096 * 1024 * 2);   // 8 MB
  bf* W0T  = (bf*)take((size_t)32 * 1024 * 2);     // 64 KB
  bf* W1b  = (bf*)take((size_t)1024 * 1024 * 2);   // 2 MB
  bf* W2b  = (bf*)take((size_t)1024 * 1024 * 2);   // 2 MB
  bf* W3b  = (bf*)take((size_t)32 * 1024 * 2);     // 64 KB
  float* tr = (float*)take((size_t)4096 * 4);      // 16 KB
  // chunk size: T0 + T1, each NB*32*1024*2 bytes; NB multiple of 8
  const size_t avail = (ws_size > off) ? (ws_size - off) : 0;
  int NB = 2048;
  while (NB > 256 && 2 * (size_t)NB * 65536 > avail) NB >>= 1;
  bf* T0 = (bf*)take((size_t)NB * 65536);
  bf* T1 = (bf*)take((size_t)NB * 65536);

  hipMemsetAsync(tr, 0, 4096 * sizeof(float), stream);
  conv_k<<<dim3(1024), dim3(256), 0, stream>>>(W1, W1b, 262144);
  conv_k<<<dim3(1024), dim3(256), 0, stream>>>(W2, W2b, 262144);
  conv_k<<<dim3(32),   dim3(256), 0, stream>>>(W3, W3b, 8192);
  w0t_k<<<dim3(128), dim3(256), 0, stream>>>(W0, W0T);
  fwd0_k<<<dim3(128), dim3(256), 0, stream>>>(z, tin, W0, b0, h0);
  gemm_fwd<<<dim3(512), dim3(256), 0, stream>>>(h0, W1b, b1, h1);
  gemm_fwd<<<dim3(512), dim3(256), 0, stream>>>(h1, W2b, b2, h2);
  fwd3_k<<<dim3(512), dim3(256), 0, stream>>>(h2, W3b, b3, out);
  for (int cb = 0; cb < 4096; cb += NB) {
    t0_k<<<dim3(NB * 8), dim3(256), 0, stream>>>(h0 + (size_t)cb * 1024, W0T, T0);
    gemm_jvp1<<<dim3(NB), dim3(256), 0, stream>>>(
        T0, W1b, h1 + (size_t)cb * 1024, T1);
    gemm_jvp2<<<dim3(NB), dim3(256), 0, stream>>>(
        T1, W2b, W3b, h2 + (size_t)cb * 1024, tr + cb);
  }
  divv_k<<<dim3(16), dim3(256), 0, stream>>>(tr, out + 131072);
}